// Round 10
// baseline (15419.460 us; speedup 1.0000x reference)
//
#include <hip/hip_runtime.h>
#include <hip/hip_bf16.h>
#include <stdint.h>

// Neural CDE, B=256 T=512 D=64 H=128 W=256.
// Round 10: r3 protocol, re-tiled for 2 WGs/CU phase overlap.
//  - 512 WGs x 256 threads (4 waves) = 2 WGs/CU; per-CU work identical to r3.
//  - 16 groups (16 rows) x 32 WGs (256 HD-cols = 4 h); wave wv owns h = 4j+wv.
//  - launch_bounds(256,2): VGPR ceiling 256 (8 waves/CU) - frags fit at last.
//  - all weight frags hoisted into register arrays per phase (r8/r9 lesson).
//  - 3 barriers/step; direct publish from wave (2 shuffles, no pbuf/combine).
//  - tagged bf16 push-exchange, 2-slot ping-pong, relaxed agent atomics (r3).
// dt = 1, frac = 0 for k<=510 => deriv = coeffs_b[:,k]; k=511 => b+2c+3d at idx 510.

#define BB 256
#define DD 64
#define HH 128
#define WW 256
#define HD 8192
#define TSTEPS 512
#define PAD_Y 136    // bf16 row stride for yb
#define PAD_G 264    // bf16 row stride for g0/g1

typedef __bf16 bf16x8 __attribute__((ext_vector_type(8)));
typedef __bf16 bf16x4 __attribute__((ext_vector_type(4)));
typedef float f32x4 __attribute__((ext_vector_type(4)));

__device__ __forceinline__ float softplus_f(float x) {
  return (x > 15.f) ? x : __logf(1.f + __expf(x));
}
__device__ __forceinline__ float tanh_f(float x) {
  float e = __expf(2.f * x);
  return 1.f - 2.f / (e + 1.f);
}
__device__ __forceinline__ uint32_t aload(const uint32_t* p) {
  return __hip_atomic_load(p, __ATOMIC_RELAXED, __HIP_MEMORY_SCOPE_AGENT);
}
__device__ __forceinline__ void publish_y(uint32_t* slot, int idx, float val, uint32_t tag) {
  unsigned short ub = __builtin_bit_cast(unsigned short, (__bf16)val);
  __hip_atomic_store(&slot[idx], (tag << 16) | (uint32_t)ub,
                     __ATOMIC_RELAXED, __HIP_MEMORY_SCOPE_AGENT);
}

__global__ void prep_kernel(const float* __restrict__ w0, const float* __restrict__ w1,
                            const float* __restrict__ w2,
                            __bf16* __restrict__ w0b, __bf16* __restrict__ w1b,
                            __bf16* __restrict__ w2b) {
  int stride = gridDim.x * blockDim.x;
  int i0 = blockIdx.x * blockDim.x + threadIdx.x;
  for (int i = i0; i < WW * HH; i += stride) w0b[i] = (__bf16)w0[i];
  for (int i = i0; i < WW * WW; i += stride) w1b[i] = (__bf16)w1[i];
  for (int i = i0; i < HD * WW; i += stride) w2b[i] = (__bf16)w2[i];
}

__global__ __launch_bounds__(256) void init_kernel(
    const float* __restrict__ ca, const float* __restrict__ iw0, const float* __restrict__ ib0,
    const float* __restrict__ iw1, const float* __restrict__ ib1,
    const float* __restrict__ iw2, const float* __restrict__ ib2,
    float* __restrict__ y0) {
  __shared__ float x0[DD];
  __shared__ float h0[WW];
  __shared__ float h1[WW];
  int b = blockIdx.x, t = threadIdx.x;
  if (t < DD) x0[t] = ca[((size_t)b * 511) * DD + t];
  __syncthreads();
  float a = ib0[t];
  for (int d = 0; d < DD; ++d) a = fmaf(x0[d], iw0[t * DD + d], a);
  h0[t] = fmaxf(a, 0.f);
  __syncthreads();
  a = ib1[t];
  for (int d = 0; d < WW; ++d) a = fmaf(h0[d], iw1[t * WW + d], a);
  h1[t] = fmaxf(a, 0.f);
  __syncthreads();
  if (t < HH) {
    a = ib2[t];
    for (int d = 0; d < WW; ++d) a = fmaf(h1[d], iw2[t * WW + d], a);
    y0[b * HH + t] = a;
  }
}

// Persistent step kernel: 512 WGs x 256 threads (2 WGs/CU), loops k=0..511.
__global__ __launch_bounds__(256, 2) void step_persist(
    const __bf16* __restrict__ w0b, const __bf16* __restrict__ w1b, const __bf16* __restrict__ w2b,
    const float* __restrict__ fb0, const float* __restrict__ fb1, const float* __restrict__ fb2,
    const float* __restrict__ cbp, const float* __restrict__ ccp, const float* __restrict__ cdp,
    float* __restrict__ yA, uint32_t* __restrict__ pk)
{
  __shared__ __align__(16) __bf16 yb[16 * PAD_Y];
  __shared__ __align__(16) __bf16 g0s[16 * PAD_G];
  __shared__ __align__(16) __bf16 g1s[16 * PAD_G];

  const int tid = threadIdx.x;
  const int wv = tid >> 6;      // 4 waves
  const int l = tid & 63;
  const int l16 = l & 15;
  const int lq = l >> 4;

  const int wid = blockIdx.x;
  const int grp = wid >> 5;     // 16 groups
  const int j = wid & 31;       // 32 WGs per group
  const int rb = grp * 16;      // batch row base (16 rows)
  const int c0 = j * 256;       // HD col base (4 h)

  // biases: stage-A cols wv*64 + cg*16 + lq*4 (cg = 0..3); gemm2 same col window
  f32x4 b0r[4], b1r[4], b2r[4];
  #pragma unroll
  for (int cg = 0; cg < 4; ++cg) {
    b0r[cg] = *(const f32x4*)&fb0[wv * 64 + cg * 16 + lq * 4];
    b1r[cg] = *(const f32x4*)&fb1[wv * 64 + cg * 16 + lq * 4];
    b2r[cg] = *(const f32x4*)&fb2[c0 + wv * 64 + cg * 16 + lq * 4];
  }

  // deriv base: row = rb + l16, d = cg*16 + lq*4 (+r)
  const size_t dvbase = ((size_t)(rb + l16) * 511) * DD + lq * 4;

  // register-resident f32 state: lane l<16 of wave wv owns (row rb+l, h = 4j+wv)
  const int myidx = (rb + l16) * HH + (4 * j + wv);
  float yreg = 0.f;
  if (l < 16) {
    yreg = yA[myidx];
    publish_y(pk, myidx, yreg, 1u);   // S_0 -> slot 0, tag 1
  }

  for (int k = 0; k < TSTEPS; ++k) {
    const uint32_t want = (uint32_t)(k + 1);
    const uint32_t* src = pk + (size_t)(k & 1) * (BB * HH);
    uint32_t* dst = pk + (size_t)((k + 1) & 1) * (BB * HH);

    // ---- deriv loads into regs (issued early; consumed in gemm2)
    f32x4 dvv[4];
    {
      size_t ko = dvbase + (size_t)((k <= 510) ? k : 510) * DD;
      #pragma unroll
      for (int cg = 0; cg < 4; ++cg) dvv[cg] = *(const f32x4*)&cbp[ko + cg * 16];
      if (k == 511) {
        #pragma unroll
        for (int cg = 0; cg < 4; ++cg) {
          f32x4 cc = *(const f32x4*)&ccp[ko + cg * 16];
          f32x4 dd = *(const f32x4*)&cdp[ko + cg * 16];
          #pragma unroll
          for (int r = 0; r < 4; ++r) dvv[cg][r] += 2.f * cc[r] + 3.f * dd[r];
        }
      }
    }

    // ---- poll this group's 16x128 y words (8 per thread), stage to yb
    {
      uint32_t v[8];
      int ad[8];
      #pragma unroll
      for (int q = 0; q < 8; ++q) {
        int i = tid + q * 256;
        ad[q] = (rb + (i >> 7)) * HH + (i & 127);
        v[q] = aload(&src[ad[q]]);
      }
      int spins = 0;
      bool allok;
      do {
        allok = true;
        #pragma unroll
        for (int q = 0; q < 8; ++q) {
          if ((v[q] >> 16) != want) {
            allok = false;
            v[q] = aload(&src[ad[q]]);
          }
        }
        if (!allok) {
          __builtin_amdgcn_s_sleep(1);
          if (++spins > (1 << 20)) break;   // structurally impossible; bail visibly
        }
      } while (!allok);
      #pragma unroll
      for (int q = 0; q < 8; ++q) {
        int i = tid + q * 256;
        yb[(i >> 7) * PAD_Y + (i & 127)] =
            __builtin_bit_cast(__bf16, (unsigned short)(v[q] & 0xFFFFu));
      }
    }
    __syncthreads();   // 1: yb ready

    // ---- gemm0 (swapped): cols wv*64 + cg*16, 16 rows; frags HOISTED
    {
      bf16x8 yf[4];
      #pragma unroll
      for (int kb = 0; kb < 4; ++kb)
        yf[kb] = *(const bf16x8*)&yb[l16 * PAD_Y + kb * 32 + lq * 8];
      #pragma unroll
      for (int cgp = 0; cgp < 2; ++cgp) {
        bf16x8 wf[4][2];
        #pragma unroll
        for (int kb = 0; kb < 4; ++kb)
          #pragma unroll
          for (int cc = 0; cc < 2; ++cc)
            wf[kb][cc] = *(const bf16x8*)&w0b[(wv * 64 + cgp * 32 + cc * 16 + l16) * HH +
                                              kb * 32 + lq * 8];
        f32x4 acc[2] = {};
        #pragma unroll
        for (int kb = 0; kb < 4; ++kb)
          #pragma unroll
          for (int cc = 0; cc < 2; ++cc)
            acc[cc] = __builtin_amdgcn_mfma_f32_16x16x32_bf16(wf[kb][cc], yf[kb], acc[cc], 0, 0, 0);
        #pragma unroll
        for (int cc = 0; cc < 2; ++cc) {
          int cg = cgp * 2 + cc;
          bf16x4 o;
          #pragma unroll
          for (int r = 0; r < 4; ++r)
            o[r] = (__bf16)softplus_f(acc[cc][r] + b0r[cg][r]);
          *(bf16x4*)&g0s[l16 * PAD_G + wv * 64 + cg * 16 + lq * 4] = o;
        }
      }
    }
    __syncthreads();   // 2: g0 ready

    // ---- gemm1 (swapped): reads g0, writes g1; frags HOISTED
    {
      bf16x8 af[8];
      #pragma unroll
      for (int kb = 0; kb < 8; ++kb)
        af[kb] = *(const bf16x8*)&g0s[l16 * PAD_G + kb * 32 + lq * 8];
      #pragma unroll
      for (int cgp = 0; cgp < 2; ++cgp) {
        bf16x8 wf[8][2];
        #pragma unroll
        for (int kb = 0; kb < 8; ++kb)
          #pragma unroll
          for (int cc = 0; cc < 2; ++cc)
            wf[kb][cc] = *(const bf16x8*)&w1b[(wv * 64 + cgp * 32 + cc * 16 + l16) * WW +
                                              kb * 32 + lq * 8];
        f32x4 acc[2] = {};
        #pragma unroll
        for (int kb = 0; kb < 8; ++kb)
          #pragma unroll
          for (int cc = 0; cc < 2; ++cc)
            acc[cc] = __builtin_amdgcn_mfma_f32_16x16x32_bf16(wf[kb][cc], af[kb], acc[cc], 0, 0, 0);
        #pragma unroll
        for (int cc = 0; cc < 2; ++cc) {
          int cg = cgp * 2 + cc;
          bf16x4 o;
          #pragma unroll
          for (int r = 0; r < 4; ++r)
            o[r] = (__bf16)softplus_f(acc[cc][r] + b1r[cg][r]);
          *(bf16x4*)&g1s[l16 * PAD_G + wv * 64 + cg * 16 + lq * 4] = o;
        }
      }
    }
    __syncthreads();   // 3: g1 ready

    // ---- gemm2: wave owns h = 4j+wv (cols c0 + wv*64 .. +63), all 64 d; HOISTED
    {
      bf16x8 af[8];
      #pragma unroll
      for (int kb = 0; kb < 8; ++kb)
        af[kb] = *(const bf16x8*)&g1s[l16 * PAD_G + kb * 32 + lq * 8];
      float pp = 0.f;
      #pragma unroll
      for (int cgp = 0; cgp < 2; ++cgp) {
        bf16x8 wf[8][2];
        #pragma unroll
        for (int kb = 0; kb < 8; ++kb)
          #pragma unroll
          for (int cc = 0; cc < 2; ++cc)
            wf[kb][cc] = *(const bf16x8*)&w2b[(size_t)(c0 + wv * 64 + cgp * 32 + cc * 16 + l16) * WW +
                                              kb * 32 + lq * 8];
        f32x4 acc[2] = {};
        #pragma unroll
        for (int kb = 0; kb < 8; ++kb)
          #pragma unroll
          for (int cc = 0; cc < 2; ++cc)
            acc[cc] = __builtin_amdgcn_mfma_f32_16x16x32_bf16(wf[kb][cc], af[kb], acc[cc], 0, 0, 0);
        #pragma unroll
        for (int cc = 0; cc < 2; ++cc) {
          int cg = cgp * 2 + cc;
          #pragma unroll
          for (int r = 0; r < 4; ++r) {
            float f = tanh_f(acc[cc][r] + b2r[cg][r]);
            pp = fmaf(f, dvv[cg][r], pp);
          }
        }
      }
      // lane: batch row = l16, d = cg*16 + lq*4 + r; reduce across lq groups
      pp += __shfl_xor(pp, 16);
      pp += __shfl_xor(pp, 32);
      if (l < 16) {
        yreg += pp;
        publish_y(dst, myidx, yreg, (uint32_t)(k + 2));
      }
    }
    // WAR safety without a 4th barrier: staging(k+1) writes yb only after this
    // thread passed barrier 3(k) and all gemm0(k) yb-reads ended before 2(k);
    // g0 writes(k+1) after 1(k+1) vs g0 reads(k) before 3(k); g1 writes(k+1)
    // after 2(k+1) vs g1 reads(k) before any thread reaches 2(k+1). All ordered.
  }

  if (l < 16) yA[myidx] = yreg;
}

__global__ __launch_bounds__(256) void final_kernel(const float* __restrict__ y,
                                                    const float* __restrict__ lw,
                                                    const float* __restrict__ lb,
                                                    float* __restrict__ out) {
  int b = threadIdx.x;
  float a = lb[0];
  for (int h = 0; h < HH; ++h) a = fmaf(y[b * HH + h], lw[h], a);
  out[b] = 1.f / (1.f + __expf(-a));
}

extern "C" void kernel_launch(void* const* d_in, const int* in_sizes, int n_in,
                              void* d_out, int out_size, void* d_ws, size_t ws_size,
                              hipStream_t stream) {
  const float* cdp = (const float*)d_in[1];
  const float* ccp = (const float*)d_in[2];
  const float* cbp = (const float*)d_in[3];
  const float* cap = (const float*)d_in[4];
  const float* iw0 = (const float*)d_in[5];
  const float* ib0 = (const float*)d_in[6];
  const float* iw1 = (const float*)d_in[7];
  const float* ib1 = (const float*)d_in[8];
  const float* iw2 = (const float*)d_in[9];
  const float* ib2 = (const float*)d_in[10];
  const float* fw0 = (const float*)d_in[11];
  const float* fb0 = (const float*)d_in[12];
  const float* fw1 = (const float*)d_in[13];
  const float* fb1 = (const float*)d_in[14];
  const float* fw2 = (const float*)d_in[15];
  const float* fb2 = (const float*)d_in[16];
  const float* lw  = (const float*)d_in[17];
  const float* lb  = (const float*)d_in[18];

  char* ws = (char*)d_ws;
  __bf16* w0b = (__bf16*)(ws);                              // 64 KB
  __bf16* w1b = (__bf16*)(ws + 65536);                      // 128 KB
  __bf16* w2b = (__bf16*)(ws + 65536 + 131072);             // 4 MB
  float* yA = (float*)(ws + 65536 + 131072 + 4194304);      // 128 KB
  uint32_t* pk = (uint32_t*)(ws + 65536 + 131072 + 4194304 + 131072);  // 256 KB (2 slots)

  hipMemsetAsync(pk, 0, 2 * BB * HH * sizeof(uint32_t), stream);
  prep_kernel<<<512, 256, 0, stream>>>(fw0, fw1, fw2, w0b, w1b, w2b);
  init_kernel<<<BB, 256, 0, stream>>>(cap, iw0, ib0, iw1, ib1, iw2, ib2, yA);
  step_persist<<<512, 256, 0, stream>>>(w0b, w1b, w2b, fb0, fb1, fb2,
                                        cbp, ccp, cdp, yA, pk);
  final_kernel<<<1, 256, 0, stream>>>(yA, lw, lb, (float*)d_out);

  (void)in_sizes; (void)n_in; (void)out_size; (void)ws_size;
}

// Round 11
// 3669.701 us; speedup vs baseline: 4.2018x; 4.2018x over previous
//
#include <hip/hip_runtime.h>
#include <hip/hip_bf16.h>
#include <stdint.h>

// Neural CDE, B=256 T=512 D=64 H=128 W=256.
// Round 11: r3 skeleton VERBATIM (8 groups x 32 WGs, redundant stage A, 5 barriers,
// 512-thread WGs, 1 WG/CU) with ONE change: flag-gated f32 exchange.
//  - producer: publish 128 f32 y-words (device-scope stores) -> trailing
//    __syncthreads (vmcnt(0) drain) -> tid==0 sets one monotone per-WG flag.
//  - consumer: thread t polls flag of source WG s=t&31 only, then bulk-reads
//    that source's 8 words (rows 2w,2w+1; h=4s..4s+3) -> no extra barrier.
//  - slot ping-pong + monotone flags: same ABA-safety argument as r3.
// dt = 1, frac = 0 for k<=510 => deriv = coeffs_b[:,k]; k=511 => b+2c+3d at idx 510.

#define BB 256
#define DD 64
#define HH 128
#define WW 256
#define HD 8192
#define TSTEPS 512
#define PAD_Y 152   // bf16 row stride for yb
#define PAD_G 280   // bf16 row stride for g0s/g1s
#define PAD_DV 68   // f32 row stride for dv

typedef __bf16 bf16x8 __attribute__((ext_vector_type(8)));
typedef __bf16 bf16x4 __attribute__((ext_vector_type(4)));
typedef float f32x4 __attribute__((ext_vector_type(4)));

__device__ __forceinline__ float softplus_f(float x) {
  return (x > 15.f) ? x : __logf(1.f + __expf(x));
}
__device__ __forceinline__ float tanh_f(float x) {
  float e = __expf(2.f * x);
  return 1.f - 2.f / (e + 1.f);
}
__device__ __forceinline__ float aloadf(const float* p) {
  return __hip_atomic_load(p, __ATOMIC_RELAXED, __HIP_MEMORY_SCOPE_AGENT);
}
__device__ __forceinline__ void astoref(float* p, float v) {
  __hip_atomic_store(p, v, __ATOMIC_RELAXED, __HIP_MEMORY_SCOPE_AGENT);
}
__device__ __forceinline__ uint32_t aloadu(const uint32_t* p) {
  return __hip_atomic_load(p, __ATOMIC_RELAXED, __HIP_MEMORY_SCOPE_AGENT);
}
__device__ __forceinline__ void astoreu(uint32_t* p, uint32_t v) {
  __hip_atomic_store(p, v, __ATOMIC_RELAXED, __HIP_MEMORY_SCOPE_AGENT);
}

__global__ void prep_kernel(const float* __restrict__ w0, const float* __restrict__ w1,
                            const float* __restrict__ w2,
                            __bf16* __restrict__ w0b, __bf16* __restrict__ w1b,
                            __bf16* __restrict__ w2b) {
  int stride = gridDim.x * blockDim.x;
  int i0 = blockIdx.x * blockDim.x + threadIdx.x;
  for (int i = i0; i < WW * HH; i += stride) w0b[i] = (__bf16)w0[i];
  for (int i = i0; i < WW * WW; i += stride) w1b[i] = (__bf16)w1[i];
  for (int i = i0; i < HD * WW; i += stride) w2b[i] = (__bf16)w2[i];
}

// y0 = MLP(coeffs_a[:,0,:]) in plain f32 (one-off, tiny)
__global__ __launch_bounds__(256) void init_kernel(
    const float* __restrict__ ca, const float* __restrict__ iw0, const float* __restrict__ ib0,
    const float* __restrict__ iw1, const float* __restrict__ ib1,
    const float* __restrict__ iw2, const float* __restrict__ ib2,
    float* __restrict__ y0) {
  __shared__ float x0[DD];
  __shared__ float h0[WW];
  __shared__ float h1[WW];
  int b = blockIdx.x, t = threadIdx.x;
  if (t < DD) x0[t] = ca[((size_t)b * 511) * DD + t];
  __syncthreads();
  float a = ib0[t];
  for (int d = 0; d < DD; ++d) a = fmaf(x0[d], iw0[t * DD + d], a);
  h0[t] = fmaxf(a, 0.f);
  __syncthreads();
  a = ib1[t];
  for (int d = 0; d < WW; ++d) a = fmaf(h0[d], iw1[t * WW + d], a);
  h1[t] = fmaxf(a, 0.f);
  __syncthreads();
  if (t < HH) {
    a = ib2[t];
    for (int d = 0; d < WW; ++d) a = fmaf(h1[d], iw2[t * WW + d], a);
    y0[b * HH + t] = a;
  }
}

// Persistent step kernel: 256 WGs x 512 threads, loops k=0..511 internally.
__global__ __launch_bounds__(512, 2) void step_persist(
    const __bf16* __restrict__ w0b, const __bf16* __restrict__ w1b, const __bf16* __restrict__ w2b,
    const float* __restrict__ fb0, const float* __restrict__ fb1, const float* __restrict__ fb2,
    const float* __restrict__ cbp, const float* __restrict__ ccp, const float* __restrict__ cdp,
    float* __restrict__ yA, float* __restrict__ pk, uint32_t* __restrict__ yflag)
{
  __shared__ __align__(16) __bf16 yb[32 * PAD_Y];
  __shared__ __align__(16) __bf16 g0s[32 * PAD_G];
  __shared__ __align__(16) __bf16 g1s[32 * PAD_G];
  __shared__ __align__(16) float dv[32 * PAD_DV];
  __shared__ float pbuf[8 * 32];

  const int tid = threadIdx.x;
  const int wv = tid >> 6;
  const int l = tid & 63;
  const int l16 = l & 15;
  const int lq = l >> 4;

  const int wid = blockIdx.x;
  const int grp = wid >> 5;
  const int j = wid & 31;
  const int rb = grp * 32;   // batch row base
  const int c0 = j * 256;    // HD col base

  // ---- loop-invariant weight fragments (A-operand role: lane l16 <-> weight col)
  bf16x8 w0f[4][2], w1f[8][2], w2f[8][2];
  #pragma unroll
  for (int c = 0; c < 2; ++c) {
    int col = wv * 32 + c * 16 + l16;
    #pragma unroll
    for (int kb = 0; kb < 4; ++kb)
      w0f[kb][c] = *(const bf16x8*)&w0b[col * HH + kb * 32 + lq * 8];
    #pragma unroll
    for (int kb = 0; kb < 8; ++kb)
      w1f[kb][c] = *(const bf16x8*)&w1b[col * WW + kb * 32 + lq * 8];
    #pragma unroll
    for (int kb = 0; kb < 8; ++kb)
      w2f[kb][c] = *(const bf16x8*)&w2b[(size_t)(c0 + col) * WW + kb * 32 + lq * 8];
  }
  // biases per output col-quad (reg dim): float4 at col = wv*32 + c*16 + lq*4
  f32x4 b0r[2], b1r[2], b2r[2];
  #pragma unroll
  for (int c = 0; c < 2; ++c) {
    b0r[c] = *(const f32x4*)&fb0[wv * 32 + c * 16 + lq * 4];
    b1r[c] = *(const f32x4*)&fb1[wv * 32 + c * 16 + lq * 4];
    b2r[c] = *(const f32x4*)&fb2[c0 + wv * 32 + c * 16 + lq * 4];
  }

  // ---- register-resident f32 state: thread tid<128 owns (row rb+(tid&31), h = 4j+(tid>>5))
  float yreg = 0.f;
  int myidx = 0;
  if (tid < 128) {
    int r = tid & 31, hl = tid >> 5;
    myidx = (rb + r) * HH + (4 * j + hl);
    yreg = yA[myidx];
    astoref(&pk[myidx], yreg);   // S_0 -> slot 0
  }
  __syncthreads();               // drain S_0 stores (all waves)
  if (tid == 0) astoreu(&yflag[grp * 32 + j], 1u);

  // staging mapping: thread t reads source WG s=t&31, rows 2w,2w+1 (w=t>>5),
  // h = 4s..4s+3 — its own flag fully guards its own reads.
  const int ps = tid & 31;
  const int pw = tid >> 5;
  const uint32_t* myflag = &yflag[grp * 32 + ps];

  for (int k = 0; k < TSTEPS; ++k) {
    const uint32_t want = (uint32_t)(k + 1);
    const float* src = pk + (size_t)(k & 1) * (BB * HH);
    float* dst = pk + (size_t)((k + 1) & 1) * (BB * HH);

    // ---- deriv loads into regs early
    float dreg[4];
    {
      int kk = (k <= 510) ? k : 510;
      #pragma unroll
      for (int q = 0; q < 4; ++q) {
        int i = tid + q * 512;
        int r = i >> 6, d = i & (DD - 1);
        int off = ((rb + r) * 511 + kk) * DD + d;
        float v = cbp[off];
        if (k == 511) v += 2.f * ccp[off] + 3.f * cdp[off];
        dreg[q] = v;
      }
    }

    // ---- flag poll (1 word/thread) + bulk-read own source's 8 y-words
    {
      int spins = 0;
      while (aloadu(myflag) < want) {
        __builtin_amdgcn_s_sleep(1);
        if (++spins > (1 << 20)) break;   // structurally impossible; bail visibly
      }
      __asm__ __volatile__("" ::: "memory");
      #pragma unroll
      for (int r2 = 0; r2 < 2; ++r2) {
        int row = 2 * pw + r2;
        const float* ysrc = &src[(rb + row) * HH + 4 * ps];
        bf16x4 o;
        #pragma unroll
        for (int q = 0; q < 4; ++q) o[q] = (__bf16)aloadf(&ysrc[q]);
        *(bf16x4*)&yb[row * PAD_Y + 4 * ps] = o;
      }
    }
    __syncthreads();   // 1: yb ready

    // ---- gemm0 (swapped): D[w0col, brow] = w0 . y
    {
      f32x4 acc[2][2] = {};
      #pragma unroll
      for (int kb = 0; kb < 4; ++kb) {
        bf16x8 y0 = *(const bf16x8*)&yb[l16 * PAD_Y + kb * 32 + lq * 8];
        bf16x8 y1 = *(const bf16x8*)&yb[(16 + l16) * PAD_Y + kb * 32 + lq * 8];
        #pragma unroll
        for (int c = 0; c < 2; ++c) {
          acc[c][0] = __builtin_amdgcn_mfma_f32_16x16x32_bf16(w0f[kb][c], y0, acc[c][0], 0, 0, 0);
          acc[c][1] = __builtin_amdgcn_mfma_f32_16x16x32_bf16(w0f[kb][c], y1, acc[c][1], 0, 0, 0);
        }
      }
      #pragma unroll
      for (int c = 0; c < 2; ++c)
        #pragma unroll
        for (int bt = 0; bt < 2; ++bt) {
          bf16x4 o;
          #pragma unroll
          for (int r = 0; r < 4; ++r)
            o[r] = (__bf16)softplus_f(acc[c][bt][r] + b0r[c][r]);
          *(bf16x4*)&g0s[(bt * 16 + l16) * PAD_G + wv * 32 + c * 16 + lq * 4] = o;
        }
    }
    // dv regs -> LDS (read in gemm2 after barrier 3)
    #pragma unroll
    for (int q = 0; q < 4; ++q) {
      int i = tid + q * 512;
      dv[(i >> 6) * PAD_DV + (i & (DD - 1))] = dreg[q];
    }
    __syncthreads();   // 2: g0 + dv ready

    // ---- gemm1 (swapped): D[w1col, brow] = w1 . g0
    {
      f32x4 acc[2][2] = {};
      #pragma unroll
      for (int kb = 0; kb < 8; ++kb) {
        bf16x8 a0 = *(const bf16x8*)&g0s[l16 * PAD_G + kb * 32 + lq * 8];
        bf16x8 a1 = *(const bf16x8*)&g0s[(16 + l16) * PAD_G + kb * 32 + lq * 8];
        #pragma unroll
        for (int c = 0; c < 2; ++c) {
          acc[c][0] = __builtin_amdgcn_mfma_f32_16x16x32_bf16(w1f[kb][c], a0, acc[c][0], 0, 0, 0);
          acc[c][1] = __builtin_amdgcn_mfma_f32_16x16x32_bf16(w1f[kb][c], a1, acc[c][1], 0, 0, 0);
        }
      }
      #pragma unroll
      for (int c = 0; c < 2; ++c)
        #pragma unroll
        for (int bt = 0; bt < 2; ++bt) {
          bf16x4 o;
          #pragma unroll
          for (int r = 0; r < 4; ++r)
            o[r] = (__bf16)softplus_f(acc[c][bt][r] + b1r[c][r]);
          *(bf16x4*)&g1s[(bt * 16 + l16) * PAD_G + wv * 32 + c * 16 + lq * 4] = o;
        }
    }
    __syncthreads();   // 3: g1 ready

    // ---- gemm2 chunk (swapped) + tanh + d-contraction
    {
      f32x4 acc[2][2] = {};
      #pragma unroll
      for (int kb = 0; kb < 8; ++kb) {
        bf16x8 a0 = *(const bf16x8*)&g1s[l16 * PAD_G + kb * 32 + lq * 8];
        bf16x8 a1 = *(const bf16x8*)&g1s[(16 + l16) * PAD_G + kb * 32 + lq * 8];
        #pragma unroll
        for (int c = 0; c < 2; ++c) {
          acc[c][0] = __builtin_amdgcn_mfma_f32_16x16x32_bf16(w2f[kb][c], a0, acc[c][0], 0, 0, 0);
          acc[c][1] = __builtin_amdgcn_mfma_f32_16x16x32_bf16(w2f[kb][c], a1, acc[c][1], 0, 0, 0);
        }
      }
      // lane holds: batch row = bt*16+l16; d = (wv&1)*32 + c*16 + lq*4 + r
      #pragma unroll
      for (int bt = 0; bt < 2; ++bt) {
        float p = 0.f;
        #pragma unroll
        for (int c = 0; c < 2; ++c) {
          f32x4 dvv = *(const f32x4*)&dv[(bt * 16 + l16) * PAD_DV +
                                         (wv & 1) * 32 + c * 16 + lq * 4];
          #pragma unroll
          for (int r = 0; r < 4; ++r) {
            float f = tanh_f(acc[c][bt][r] + b2r[c][r]);
            p = fmaf(f, dvv[r], p);
          }
        }
        p += __shfl_xor(p, 16);
        p += __shfl_xor(p, 32);
        if (l < 16) pbuf[wv * 32 + bt * 16 + l] = p;
      }
    }
    __syncthreads();   // 4: pbuf ready

    // ---- combine wave pairs (d halves), update register state, publish f32
    if (tid < 128) {
      int hl = tid >> 5, r = tid & 31;
      yreg += pbuf[(2 * hl) * 32 + r] + pbuf[(2 * hl + 1) * 32 + r];
      astoref(&dst[myidx], yreg);
    }
    __syncthreads();   // 5: drains publish stores (per-wave vmcnt(0) before s_barrier)
    if (tid == 0) astoreu(&yflag[grp * 32 + j], (uint32_t)(k + 2));
  }

  // final f32 state -> yA (kernel-end flush makes it visible to final_kernel)
  if (tid < 128) yA[myidx] = yreg;
}

__global__ __launch_bounds__(256) void final_kernel(const float* __restrict__ y,
                                                    const float* __restrict__ lw,
                                                    const float* __restrict__ lb,
                                                    float* __restrict__ out) {
  int b = threadIdx.x;
  float a = lb[0];
  for (int h = 0; h < HH; ++h) a = fmaf(y[b * HH + h], lw[h], a);
  out[b] = 1.f / (1.f + __expf(-a));
}

extern "C" void kernel_launch(void* const* d_in, const int* in_sizes, int n_in,
                              void* d_out, int out_size, void* d_ws, size_t ws_size,
                              hipStream_t stream) {
  const float* cdp = (const float*)d_in[1];
  const float* ccp = (const float*)d_in[2];
  const float* cbp = (const float*)d_in[3];
  const float* cap = (const float*)d_in[4];
  const float* iw0 = (const float*)d_in[5];
  const float* ib0 = (const float*)d_in[6];
  const float* iw1 = (const float*)d_in[7];
  const float* ib1 = (const float*)d_in[8];
  const float* iw2 = (const float*)d_in[9];
  const float* ib2 = (const float*)d_in[10];
  const float* fw0 = (const float*)d_in[11];
  const float* fb0 = (const float*)d_in[12];
  const float* fw1 = (const float*)d_in[13];
  const float* fb1 = (const float*)d_in[14];
  const float* fw2 = (const float*)d_in[15];
  const float* fb2 = (const float*)d_in[16];
  const float* lw  = (const float*)d_in[17];
  const float* lb  = (const float*)d_in[18];

  char* ws = (char*)d_ws;
  __bf16* w0b = (__bf16*)(ws);                              // 64 KB
  __bf16* w1b = (__bf16*)(ws + 65536);                      // 128 KB
  __bf16* w2b = (__bf16*)(ws + 196608);                     // 4 MB
  float* yA = (float*)(ws + 4390912);                       // 128 KB
  float* pk = (float*)(ws + 4521984);                       // 256 KB (2 slots, f32)
  uint32_t* yflag = (uint32_t*)(ws + 4784128);              // 1 KB

  hipMemsetAsync(yflag, 0, 1024, stream);
  prep_kernel<<<512, 256, 0, stream>>>(fw0, fw1, fw2, w0b, w1b, w2b);
  init_kernel<<<BB, 256, 0, stream>>>(cap, iw0, ib0, iw1, ib1, iw2, ib2, yA);
  step_persist<<<256, 512, 0, stream>>>(w0b, w1b, w2b, fb0, fb1, fb2,
                                        cbp, ccp, cdp, yA, pk, yflag);
  final_kernel<<<1, 256, 0, stream>>>(yA, lw, lb, (float*)d_out);

  (void)in_sizes; (void)n_in; (void)out_size; (void)ws_size;
}